// Round 2
// 125.117 us; speedup vs baseline: 1.0156x; 1.0156x over previous
//
#include <hip/hip_runtime.h>
#include <math.h>

#define T_STEPS 9
#define D_IN    512
#define HID     64
#define G4      256   // 4*HID
#define BPB     8     // batches per block
#define ROWS    72    // real tile rows = BPB * T_STEPS (LDS tile has 80; rows 72-79 garbage)
#define NCH     8     // K chunks of 64

typedef short  short8 __attribute__((ext_vector_type(8)));
typedef float  f32x4  __attribute__((ext_vector_type(4)));
typedef unsigned int uint;
typedef unsigned short ushort;

// ---------------------------------------------------------------------------
__device__ __forceinline__ ushort f2bf(float f) {
    uint u = __float_as_uint(f);
    u = (u + 0x7FFFu + ((u >> 16) & 1u)) >> 16;   // RNE
    return (ushort)u;
}
__device__ __forceinline__ float fsig(float x) {
    return 1.0f / (1.0f + __expf(-x));
}
__device__ __forceinline__ float ftanh(float x) {
    float t = __expf(-2.0f * fabsf(x));
    float r = (1.0f - t) / (1.0f + t);
    return copysignf(r, x);
}
// 8x f32 -> short8 bf16 via hw packed convert (RNE; D.lo = cvt(S0))
__device__ __forceinline__ short8 cvt8(f32x4 lo, f32x4 hi) {
    union { uint u[4]; short8 s; } r;
    asm("v_cvt_pk_bf16_f32 %0, %1, %2" : "=v"(r.u[0]) : "v"(lo[0]), "v"(lo[1]));
    asm("v_cvt_pk_bf16_f32 %0, %1, %2" : "=v"(r.u[1]) : "v"(lo[2]), "v"(lo[3]));
    asm("v_cvt_pk_bf16_f32 %0, %1, %2" : "=v"(r.u[2]) : "v"(hi[0]), "v"(hi[1]));
    asm("v_cvt_pk_bf16_f32 %0, %1, %2" : "=v"(r.u[3]) : "v"(hi[2]), "v"(hi[3]));
    return r.s;
}
// async global(f32,16B/lane) -> LDS; dest = uniform base + lane*16 (HW rule)
__device__ __forceinline__ void gl2lds16(const float* g, float* l) {
    __builtin_amdgcn_global_load_lds(
        (const __attribute__((address_space(1))) void*)g,
        (__attribute__((address_space(3))) void*)l, 16, 0, 0);
}

// ---------------------------------------------------------------------------
// Prepass: weights -> bf16 fragment layouts; coalesced reads AND coalesced
// 16B writes: thread (blk, n) reads 8 consecutive k rows at column n, packs
// one short8.
// WxT: [blk(64)][n(256)][j(8)], k = blk*8+j.  WhT: [kq(8)][n(256)][j(8)].
__global__ __launch_bounds__(256)
void prep_w(const float* __restrict__ kern, ushort* __restrict__ wxT,
            ushort* __restrict__ whT)
{
    const int blk = blockIdx.x;           // 0..63 -> wxT, 64..71 -> whT
    const int n   = threadIdx.x;          // 0..255
    const int krow0 = (blk < 64) ? blk * 8 : 512 + (blk - 64) * 8;
    union { ushort us[8]; short8 v; } o;
    #pragma unroll
    for (int j = 0; j < 8; ++j)
        o.us[j] = f2bf(kern[(size_t)(krow0 + j) * G4 + n]);
    if (blk < 64) *(short8*)&wxT[((size_t)blk * 256 + n) * 8] = o.v;
    else          *(short8*)&whT[((size_t)(blk - 64) * 256 + n) * 8] = o.v;
}

// ---------------------------------------------------------------------------
// Fused LSTM, R9 structure (R10 = R9 + chunk-0 DMA dest fix).
//   Phase 1: 8 chunks of K=64. x stays f32 in LDS, staged by global_load_lds
//   (dwordx4), triple-buffered (20KB/chunk). Octet swizzle (oct ^ row&7) is
//   applied by PRE-SWIZZLING the per-lane global source address (DMA dest
//   must be linear). Counted waits: per-iter s_waitcnt vmcnt(5) keeps the
//   next chunk's 5 DMAs in flight across raw s_barrier (never vmcnt(0) until
//   the last chunk). bf16 conversion happens at fragment read (cvt_pk).
//   vmcnt ledger per wave/iter k: top outstanding = [DMA_{k+1}(5)] (DMA_k
//   and bFb_{k-1} were drained by the compiler's pre-MFMA wait in iter k-1,
//   which must reach vmcnt(5) to cover the newest bFb load; in-order
//   completion makes that drain DMA_k too -> chunk-k visibility holds at the
//   top-of-iter-k barrier).
//   Phase 2: parity recurrence, ONE raw barrier/step (lgkmcnt(0)+s_barrier;
//   step-s writes go to the inactive-parity sH rows, disjoint from the rows
//   that feed active C rows; out-stores are never vmcnt-drained).
__global__ __launch_bounds__(256, 2)
void lstm_fused(const float* __restrict__ x, const ushort* __restrict__ wxT,
                const ushort* __restrict__ whT, const float* __restrict__ bias,
                float* __restrict__ out)
{
    __shared__ float  sX[3][80 * 64];     // 3 x 20 KB chunk buffers (f32)
    __shared__ ushort sH[1024];           // 2 KB [kq(8)][m(16)][j(8)]

    const int t = threadIdx.x;
    const int w = t >> 6, l = t & 63;
    const int lane15 = l & 15, quad = l >> 4;
    const int u = w * 16 + lane15;

    // ---- per-lane DMA source offsets (floats) for this wave's 5 instrs.
    // DMA instr m = w*5+j covers LDS rows 4m..4m+3 (64 f32 each, linear).
    // lane l -> row = 4m + (l>>4), 16B segment (l&15). LDS octet p holds
    // source octet p ^ (row&7) (inverse of the read-side swizzle).
    // tile row = s*8+b -> x row b*9+s; rows 72-79 clamp to s=8 (garbage ok:
    // their C rows are never stored).
    const float* xbase = x + (size_t)blockIdx.x * (ROWS * D_IN);
    int soff[5];
    #pragma unroll
    for (int j = 0; j < 5; ++j) {
        int m   = w * 5 + j;
        int row = m * 4 + (l >> 4);
        int b_  = row & 7, s_ = row >> 3;
        int xr  = b_ * 9 + (s_ < 9 ? s_ : 8);
        int oct = ((l & 15) >> 1) ^ (row & 7);
        soff[j] = xr * 512 + oct * 8 + (l & 1) * 4;
    }

    // ---- prologue: issue DMA for chunks 0 and 1 (oldest-first order pinned)
    #pragma unroll
    for (int j = 0; j < 5; ++j)
        gl2lds16(xbase + soff[j] + 0 * 64, &sX[0][(w * 5 + j) * 256]);
    __builtin_amdgcn_sched_barrier(0);
    #pragma unroll
    for (int j = 0; j < 5; ++j)
        gl2lds16(xbase + soff[j] + 1 * 64, &sX[1][(w * 5 + j) * 256]);
    __builtin_amdgcn_sched_barrier(0);

    // ---- zero sH (h_0 = 0); lgkm-drain so it's visible after first barrier
    if (t < 128) {
        uint4 z = {0u, 0u, 0u, 0u};
        *(uint4*)&sH[t * 8] = z;
    }
    asm volatile("s_waitcnt lgkmcnt(0)" ::: "memory");

    // =============  Phase 1: pipelined K-chunks  ===============
    f32x4 acc[5][4];
    #pragma unroll
    for (int i = 0; i < 5; ++i)
        #pragma unroll
        for (int g = 0; g < 4; ++g)
            acc[i][g] = (f32x4){0.f, 0.f, 0.f, 0.f};

    short8 bFb[2][4];

    #pragma unroll
    for (int k = 0; k < NCH; ++k) {
        if (k < NCH - 1) asm volatile("s_waitcnt vmcnt(5)" ::: "memory");
        else             asm volatile("s_waitcnt vmcnt(0)" ::: "memory");
        __builtin_amdgcn_sched_barrier(0);
        __builtin_amdgcn_s_barrier();          // chunk k LDS-visible to all
        __builtin_amdgcn_sched_barrier(0);

        // Wx fragments for this chunk (L2-hot; compiler waits before MFMA use)
        #pragma unroll
        for (int kk = 0; kk < 2; ++kk)
            #pragma unroll
            for (int g = 0; g < 4; ++g)
                bFb[kk][g] = *(const short8*)
                    &wxT[(size_t)(((k * 2 + kk) * 4 + quad) * 256 + g * 64 + u) * 8];
        __builtin_amdgcn_sched_barrier(0);

        // issue DMA for chunk k+2 (buffer (k+2)%3 = (k-1)%3: its readers
        // finished before the barrier above)
        if (k < NCH - 2) {
            float* dst = &sX[(k + 2) % 3][0];
            #pragma unroll
            for (int j = 0; j < 5; ++j)
                gl2lds16(xbase + soff[j] + (k + 2) * 64, dst + (w * 5 + j) * 256);
        }
        __builtin_amdgcn_sched_barrier(0);

        // compute chunk k: ds_read_b128 x2 + cvt_pk -> 4 MFMA per (kk,i)
        #pragma unroll
        for (int kk = 0; kk < 2; ++kk) {
            #pragma unroll
            for (int i = 0; i < 5; ++i) {
                int row = i * 16 + lane15;
                int op  = (((kk * 4 + quad) ^ (row & 7)) << 3);
                f32x4 lo = *(const f32x4*)&sX[k % 3][row * 64 + op];
                f32x4 hi = *(const f32x4*)&sX[k % 3][row * 64 + op + 4];
                short8 aF = cvt8(lo, hi);
                #pragma unroll
                for (int g = 0; g < 4; ++g)
                    acc[i][g] = __builtin_amdgcn_mfma_f32_16x16x32_bf16(
                        aF, bFb[kk][g], acc[i][g], 0, 0, 0);
            }
        }
    }

    // =======================  Phase 2: recurrence  ========================
    short8 whF[4][2];
    #pragma unroll
    for (int g = 0; g < 4; ++g)
        #pragma unroll
        for (int kh = 0; kh < 2; ++kh)
            whF[g][kh] = *(const short8*)&whT[(size_t)((kh * 4 + quad) * 256 + g * 64 + u) * 8];

    float bia[4];
    bia[0] = bias[u];
    bia[1] = bias[64 + u];
    bia[2] = bias[128 + u] + 1.0f;       // FORGET_BIAS folded
    bia[3] = bias[192 + u];

    float cst[4] = {0.f, 0.f, 0.f, 0.f};
    const int b0 = blockIdx.x * BPB;

    #pragma unroll                         // static acc[] indices
    for (int s = 0; s < T_STEPS; ++s) {
        const int  i = s >> 1;
        const int  p = s & 1;
        const bool active = ((quad >> 1) == p);   // quads {2p,2p+1} hold step s
        const int  bofs = (quad & 1) * 4;         // batch = bofs + r

        f32x4 g4[4];
        #pragma unroll
        for (int g = 0; g < 4; ++g)
            #pragma unroll
            for (int r = 0; r < 4; ++r)
                g4[g][r] = acc[i][g][r] + bia[g];

        // h_{s-1} fragments: active C rows (8p..8p+7) depend only on A rows
        // 8p..8p+7 = sH rows holding h_{s-1}; other rows feed inactive C rows.
        short8 aF[2];
        #pragma unroll
        for (int kh = 0; kh < 2; ++kh)
            aF[kh] = *(const short8*)&sH[((kh * 4 + quad) * 16 + lane15) * 8];

        #pragma unroll
        for (int g = 0; g < 4; ++g)
            #pragma unroll
            for (int kh = 0; kh < 2; ++kh)
                g4[g] = __builtin_amdgcn_mfma_f32_16x16x32_bf16(aF[kh], whF[g][kh], g4[g], 0, 0, 0);

        const int wrow = 8 * ((s + 1) & 1);   // rows for h_s = next parity
        #pragma unroll
        for (int r = 0; r < 4; ++r) {
            float cp = __shfl_xor(cst[r], 32);   // partner quad's c_{s-1}
            if (active) {
                float ii = fsig(g4[0][r]);
                float jj = ftanh(g4[1][r]);
                float ff = fsig(g4[2][r]);
                float oo = fsig(g4[3][r]);
                float c  = ff * cp + ii * jj;
                cst[r] = c;
                float h = oo * ftanh(c);
                int bb = bofs + r;
                out[((size_t)(b0 + bb) * T_STEPS + s) * HID + u] = h;
                sH[((u >> 3) * 16 + wrow + bb) * 8 + (u & 7)] = f2bf(h);
            }
        }
        // single barrier/step: own ds_writes drained (lgkm), out-stores NOT
        // drained (raw s_barrier, no vmcnt(0))
        asm volatile("s_waitcnt lgkmcnt(0)" ::: "memory");
        __builtin_amdgcn_sched_barrier(0);
        __builtin_amdgcn_s_barrier();
        __builtin_amdgcn_sched_barrier(0);
    }
}

// ---------------------------------------------------------------------------
extern "C" void kernel_launch(void* const* d_in, const int* in_sizes, int n_in,
                              void* d_out, int out_size, void* d_ws, size_t ws_size,
                              hipStream_t stream)
{
    const float* x    = (const float*)d_in[0];
    const float* kern = (const float*)d_in[1];
    const float* bias = (const float*)d_in[2];
    float* out = (float*)d_out;

    const int B = in_sizes[0] / (T_STEPS * D_IN);   // 4096

    ushort* wxT = (ushort*)d_ws;                    // 256 KB
    ushort* whT = (ushort*)((char*)d_ws + 262144);  // 32 KB

    prep_w<<<72, 256, 0, stream>>>(kern, wxT, whT);
    lstm_fused<<<B / BPB, 256, 0, stream>>>(x, wxT, whT, bias, out);
}